// Round 4
// baseline (294.139 us; speedup 1.0000x reference)
//
#include <hip/hip_runtime.h>
#include <cstdint>
#include <cstddef>

// Problem constants (from reference): B=2, T=2048, C=1024, H=16, hs=64
// Harness dtypes: inputs fp32, output fp32; internal compute bf16 MFMA.
#define BB 2
#define TT 2048
#define CC 1024
#define HH 16
#define HS 64
#define MM (BB*TT)      // 4096 rows
#define N1 (3*CC)       // 3072 qkv cols

// P-scratch row stride (elements); 40 breaks the stride-32 bank pattern
#define PST 40

typedef __bf16 bf16_t;
typedef bf16_t bf16x8 __attribute__((ext_vector_type(8)));
typedef float  floatx4 __attribute__((ext_vector_type(4)));

__device__ __forceinline__ bf16_t f2bf(float f) {
    uint32_t u = __builtin_bit_cast(uint32_t, f);
    u += 0x7FFFu + ((u >> 16) & 1u);   // round-to-nearest-even
    unsigned short s = (unsigned short)(u >> 16);
    return __builtin_bit_cast(bf16_t, s);
}

__device__ __forceinline__ void load_lds16(const bf16_t* g, bf16_t* l) {
    // async global->LDS, 16B per lane; LDS dst = wave-uniform base + lane*16
    __builtin_amdgcn_global_load_lds((__attribute__((address_space(1))) void*)g,
                                     (__attribute__((address_space(3))) void*)l,
                                     16, 0, 0);
}

// ---------------------------------------------------------------- pack x
__global__ __launch_bounds__(256) void k_pack(const float* __restrict__ src,
                                              bf16_t* __restrict__ dst) {
    size_t i = ((size_t)blockIdx.x * 256 + threadIdx.x) * 8;
    float4 a = *(const float4*)(src + i);
    float4 b = *(const float4*)(src + i + 4);
    bf16x8 o;
    o[0] = f2bf(a.x); o[1] = f2bf(a.y); o[2] = f2bf(a.z); o[3] = f2bf(a.w);
    o[4] = f2bf(b.x); o[5] = f2bf(b.y); o[6] = f2bf(b.z); o[7] = f2bf(b.w);
    *(bf16x8*)(dst + i) = o;
}

// ---------------------------------------------------------------- transpose+cvt
__global__ __launch_bounds__(256) void k_transpose(const float* __restrict__ src,
                                                   bf16_t* __restrict__ dst,
                                                   int R, int Ccol) {
    __shared__ bf16_t tile[32][33];
    int c0 = blockIdx.x * 32, r0 = blockIdx.y * 32;
    int tx = threadIdx.x, ty = threadIdx.y;
    for (int i = ty; i < 32; i += 8)
        tile[i][tx] = f2bf(src[(size_t)(r0 + i) * Ccol + c0 + tx]);
    __syncthreads();
    for (int i = ty; i < 32; i += 8)
        dst[(size_t)(c0 + i) * R + r0 + tx] = tile[tx][i];
}

// ---------------------------------------------------------------- GEMM core
__device__ __forceinline__ void gemm_core(const bf16_t* __restrict__ A,
                                          const bf16_t* __restrict__ Bt,
                                          bf16_t* As, bf16_t* Bs,
                                          int m0, int n0, int K,
                                          floatx4 acc[4][4]) {
    const int tid = threadIdx.x;
    const int wave = tid >> 6, lane = tid & 63;
    const int quad = lane >> 4, lrow = lane & 15;
    const int wm = wave >> 1, wn = wave & 1;
    const int lsub = lane >> 2;   // 0..15 row within 16-row group
    const int kc = lane & 3;      // k-chunk (8 bf16 = 16B)

    for (int kk = 0; kk < K; kk += 32) {
        for (int s = 0; s < 2; ++s) {
            int rg = wave * 2 + s;  // 16-row group 0..7
            const bf16_t* ga = A  + (size_t)(m0 + rg * 16 + lsub) * K + kk + kc * 8;
            const bf16_t* gb = Bt + (size_t)(n0 + rg * 16 + lsub) * K + kk + kc * 8;
            load_lds16(ga, As + rg * 512);
            load_lds16(gb, Bs + rg * 512);
        }
        __syncthreads();
        bf16x8 af[4], bfr[4];
        for (int i = 0; i < 4; ++i)
            af[i] = *(const bf16x8*)(As + (wm * 64 + i * 16 + lrow) * 32 + quad * 8);
        for (int j = 0; j < 4; ++j)
            bfr[j] = *(const bf16x8*)(Bs + (wn * 64 + j * 16 + lrow) * 32 + quad * 8);
        for (int i = 0; i < 4; ++i)
            for (int j = 0; j < 4; ++j)
                acc[i][j] = __builtin_amdgcn_mfma_f32_16x16x32_bf16(af[i], bfr[j], acc[i][j], 0, 0, 0);
        __syncthreads();
    }
}

// ---------------------------------------------------------------- QKV GEMM
__global__ __launch_bounds__(256, 2) void k_gemm_qkv(const bf16_t* __restrict__ x,
                                                     const bf16_t* __restrict__ Wt,
                                                     bf16_t* __restrict__ qb,
                                                     bf16_t* __restrict__ kb,
                                                     bf16_t* __restrict__ vb) {
    __shared__ bf16_t As[128 * 32];
    __shared__ bf16_t Bs[128 * 32];
    const int m0 = blockIdx.y * 128, n0 = blockIdx.x * 128;
    floatx4 acc[4][4];
    for (int i = 0; i < 4; ++i)
        for (int j = 0; j < 4; ++j)
            acc[i][j] = floatx4{0.f, 0.f, 0.f, 0.f};
    gemm_core(x, Wt, As, Bs, m0, n0, CC, acc);

    const int tid = threadIdx.x, wave = tid >> 6, lane = tid & 63;
    const int quad = lane >> 4, lrow = lane & 15;
    const int wm = wave >> 1, wn = wave & 1;
    for (int i = 0; i < 4; ++i)
        for (int j = 0; j < 4; ++j) {
            int gn = n0 + wn * 64 + j * 16 + lrow;
            int which = gn >> 10, c = gn & 1023, h = c >> 6, d = c & 63;
            for (int r = 0; r < 4; ++r) {
                int gm = m0 + wm * 64 + i * 16 + quad * 4 + r;
                int b = gm >> 11, t = gm & 2047;
                float val = acc[i][j][r];
                if (which == 0)
                    qb[((size_t)(b * HH + h) * TT + t) * HS + d] = f2bf(val * 0.125f);
                else if (which == 1)
                    kb[((size_t)(b * HH + h) * TT + t) * HS + d] = f2bf(val);
                else
                    vb[((size_t)(b * HH + h) * HS + d) * TT + t] = f2bf(val);
            }
        }
}

// ---------------------------------------------------------------- attention
// One wave per 16-query tile; 32-key tiles. No-max softmax (exact: max
// cancels in softmax; scores ~N(0,1) so exp() is fp32-safe). l reduced once
// after the loop. P is software-pipelined through LDS by ONE TILE:
// iteration t reads P(t-1) (ping-pong buffer) BEFORE writing P(t); DS ops
// complete in-order, so the read's own wait covers last iter's writes and
// the same-iteration write->drain->read chain disappears.
// Block = 4 consecutive qt (trip counts differ by <=1 -> no intra-block
// idle); blocks dispatched longest-first.
__global__ __launch_bounds__(256, 4) void k_attn(const bf16_t* __restrict__ qb,
                                                 const bf16_t* __restrict__ kb,
                                                 const bf16_t* __restrict__ vt,
                                                 bf16_t* __restrict__ y) {
    __shared__ bf16_t Ps[4 * 2 * 16 * PST];   // per-wave ping-pong P buffers
    const int tid = threadIdx.x, wave = tid >> 6, lane = tid & 63;
    const int quad = lane >> 4, lrow = lane & 15;
    const int bh = blockIdx.x & 31;            // b*H + h (fast dim: L2 spread)
    const int qg = 31 - (blockIdx.x >> 5);     // query group, longest first
    const int qt = qg * 4 + wave;              // 16-query tile

    const bf16_t* Q = qb + (size_t)bh * TT * HS;
    const bf16_t* K = kb + (size_t)bh * TT * HS;
    const bf16_t* V = vt + (size_t)bh * HS * TT;

    bf16x8 aq[2];
    aq[0] = *(const bf16x8*)(Q + (size_t)(qt * 16 + lrow) * HS + quad * 8);
    aq[1] = *(const bf16x8*)(Q + (size_t)(qt * 16 + lrow) * HS + 32 + quad * 8);

    floatx4 o[4];
    for (int dc = 0; dc < 4; ++dc) o[dc] = floatx4{0.f, 0.f, 0.f, 0.f};
    float lsum[4] = {0.f, 0.f, 0.f, 0.f};

    bf16_t* P0 = Ps + wave * 2 * 16 * PST;     // buffer for even tiles
    bf16_t* P1 = P0 + 16 * PST;                // buffer for odd tiles
    const int nt = qt / 2 + 1;                 // # 32-key tiles

    // preload first K tile
    bf16x8 bk[4];
    bk[0] = *(const bf16x8*)(K + (size_t)(lrow) * HS + quad * 8);
    bk[1] = *(const bf16x8*)(K + (size_t)(lrow) * HS + 32 + quad * 8);
    bk[2] = *(const bf16x8*)(K + (size_t)(16 + lrow) * HS + quad * 8);
    bk[3] = *(const bf16x8*)(K + (size_t)(16 + lrow) * HS + 32 + quad * 8);

    bf16x8 bv_sav[4];   // V frags of tile t-1, consumed by the deferred PV

    for (int t = 0; t < nt; ++t) {
        const int j0 = t * 32;
        // ---- QK^T for tile t
        floatx4 s0 = floatx4{0.f, 0.f, 0.f, 0.f};
        floatx4 s1 = floatx4{0.f, 0.f, 0.f, 0.f};
        s0 = __builtin_amdgcn_mfma_f32_16x16x32_bf16(aq[0], bk[0], s0, 0, 0, 0);
        s0 = __builtin_amdgcn_mfma_f32_16x16x32_bf16(aq[1], bk[1], s0, 0, 0, 0);
        s1 = __builtin_amdgcn_mfma_f32_16x16x32_bf16(aq[0], bk[2], s1, 0, 0, 0);
        s1 = __builtin_amdgcn_mfma_f32_16x16x32_bf16(aq[1], bk[3], s1, 0, 0, 0);

        // ---- prefetch next K tile (clamped dummy re-read on last iter)
        int jn = (t + 1 < nt) ? (j0 + 32) : j0;
        bk[0] = *(const bf16x8*)(K + (size_t)(jn + lrow) * HS + quad * 8);
        bk[1] = *(const bf16x8*)(K + (size_t)(jn + lrow) * HS + 32 + quad * 8);
        bk[2] = *(const bf16x8*)(K + (size_t)(jn + 16 + lrow) * HS + quad * 8);
        bk[3] = *(const bf16x8*)(K + (size_t)(jn + 16 + lrow) * HS + 32 + quad * 8);

        // ---- deferred PV for tile t-1 (read issued BEFORE this tile's writes)
        if (t > 0) {
            const bf16_t* Pr = (t & 1) ? P0 : P1;   // (t-1)'s buffer
            bf16x8 pa = *(const bf16x8*)(Pr + lrow * PST + quad * 8);
            for (int dc = 0; dc < 4; ++dc)
                o[dc] = __builtin_amdgcn_mfma_f32_16x16x32_bf16(pa, bv_sav[dc], o[dc], 0, 0, 0);
        }

        // ---- V frags of tile t (used next iteration / epilogue)
        for (int dc = 0; dc < 4; ++dc)
            bv_sav[dc] = *(const bf16x8*)(V + (size_t)(dc * 16 + lrow) * TT + j0 + quad * 8);

        // ---- exp + causal mask, accumulate per-lane l
        float p0[4], p1[4];
        for (int r = 0; r < 4; ++r) {
            int qi = qt * 16 + quad * 4 + r;
            p0[r] = (j0 + lrow <= qi)      ? __expf(s0[r]) : 0.f;
            p1[r] = (j0 + 16 + lrow <= qi) ? __expf(s1[r]) : 0.f;
            lsum[r] += p0[r] + p1[r];
        }

        // ---- write P(t) to its ping-pong buffer
        bf16_t* Pw = (t & 1) ? P1 : P0;
        for (int r = 0; r < 4; ++r) {
            Pw[(quad * 4 + r) * PST + lrow]      = f2bf(p0[r]);
            Pw[(quad * 4 + r) * PST + 16 + lrow] = f2bf(p1[r]);
        }
    }

    // ---- final deferred PV (last tile)
    {
        const bf16_t* Pr = (nt & 1) ? P0 : P1;   // (nt-1)'s buffer
        bf16x8 pa = *(const bf16x8*)(Pr + lrow * PST + quad * 8);
        for (int dc = 0; dc < 4; ++dc)
            o[dc] = __builtin_amdgcn_mfma_f32_16x16x32_bf16(pa, bv_sav[dc], o[dc], 0, 0, 0);
    }

    // one-time l reduction across the 16 lanes sharing each row
    float inv[4];
    for (int r = 0; r < 4; ++r) {
        float s = lsum[r];
        s += __shfl_xor(s, 1, 64);
        s += __shfl_xor(s, 2, 64);
        s += __shfl_xor(s, 4, 64);
        s += __shfl_xor(s, 8, 64);
        inv[r] = 1.0f / s;
    }

    const int b = bh >> 4, h = bh & 15;
    for (int r = 0; r < 4; ++r) {
        int t = qt * 16 + quad * 4 + r;
        for (int dc = 0; dc < 4; ++dc)
            y[(size_t)(b * TT + t) * CC + h * HS + dc * 16 + lrow] = f2bf(o[dc][r] * inv[r]);
    }
}

// ---------------------------------------------------------------- out GEMM (fp32 out + bias)
__global__ __launch_bounds__(256, 2) void k_gemm_out(const bf16_t* __restrict__ yin,
                                                     const bf16_t* __restrict__ Wt,
                                                     const float* __restrict__ bias,
                                                     float* __restrict__ out) {
    __shared__ bf16_t As[128 * 32];
    __shared__ bf16_t Bs[128 * 32];
    const int m0 = blockIdx.y * 128, n0 = blockIdx.x * 128;
    floatx4 acc[4][4];
    for (int i = 0; i < 4; ++i)
        for (int j = 0; j < 4; ++j)
            acc[i][j] = floatx4{0.f, 0.f, 0.f, 0.f};
    gemm_core(yin, Wt, As, Bs, m0, n0, CC, acc);

    const int tid = threadIdx.x, wave = tid >> 6, lane = tid & 63;
    const int quad = lane >> 4, lrow = lane & 15;
    const int wm = wave >> 1, wn = wave & 1;
    for (int i = 0; i < 4; ++i)
        for (int j = 0; j < 4; ++j) {
            int gn = n0 + wn * 64 + j * 16 + lrow;
            float bb = bias[gn];
            for (int r = 0; r < 4; ++r) {
                int gm = m0 + wm * 64 + i * 16 + quad * 4 + r;
                out[(size_t)gm * CC + gn] = acc[i][j][r] + bb;
            }
        }
}

// ---------------------------------------------------------------- launch
extern "C" void kernel_launch(void* const* d_in, const int* in_sizes, int n_in,
                              void* d_out, int out_size, void* d_ws, size_t ws_size,
                              hipStream_t stream) {
    (void)in_sizes; (void)n_in; (void)out_size; (void)ws_size;
    const float* x    = (const float*)d_in[0];  // [2,2048,1024] fp32
    const float* Wqkv = (const float*)d_in[1];  // [1024,3072]   fp32
    const float* Wout = (const float*)d_in[2];  // [1024,1024]   fp32
    const float* bout = (const float*)d_in[3];  // [1024]        fp32
    float* out = (float*)d_out;                 // [2,2048,1024] fp32

    bf16_t* xb  = (bf16_t*)d_ws;                        // [4096][1024]  8 MB
    bf16_t* Wt1 = xb + (size_t)MM * CC;                 // [3072][1024]  6 MB
    bf16_t* Wt2 = Wt1 + (size_t)N1 * CC;                // [1024][1024]  2 MB
    bf16_t* qb  = Wt2 + (size_t)CC * CC;                // [B,H,T,hs]    8 MB
    bf16_t* kb  = qb + (size_t)BB * HH * TT * HS;       // [B,H,T,hs]    8 MB
    bf16_t* vb  = kb + (size_t)BB * HH * TT * HS;       // [B,H,hs,T]    8 MB
    bf16_t* yb  = vb + (size_t)BB * HH * TT * HS;       // [B,T,C] bf16  8 MB

    k_pack<<<dim3((size_t)MM * CC / (256 * 8)), 256, 0, stream>>>(x, xb);
    k_transpose<<<dim3(N1 / 32, CC / 32), dim3(32, 8), 0, stream>>>(Wqkv, Wt1, CC, N1);
    k_transpose<<<dim3(CC / 32, CC / 32), dim3(32, 8), 0, stream>>>(Wout, Wt2, CC, CC);
    k_gemm_qkv<<<dim3(N1 / 128, MM / 128), 256, 0, stream>>>(xb, Wt1, qb, kb, vb);
    k_attn<<<dim3(32 * 32), 256, 0, stream>>>(qb, kb, vb, yb);
    k_gemm_out<<<dim3(CC / 128, MM / 128), 256, 0, stream>>>(yb, Wt2, bout, out);
}